// Round 9
// baseline (41.525 us; speedup 1.0000x reference)
//
#include <hip/hip_runtime.h>
#include <math.h>

#define B_ 2
#define N_ 1024
#define C_ 81
#define NFG 80            // foreground classes 1..80
#define DETS 100
#define CAND (N_ * NFG)   // per-image candidate capacity
#define SCORE_THRESH 0.05f
#define NMS_THRESH 0.5f
#define NEG_INF -1e30f
#define IMG_W_M1 1332.0f
#define IMG_H_M1 799.0f
#define XFORM_CLIP 4.135166556742356f   // log(1000/16)
#define HB 192            // coarse score-histogram buckets
#define LCAP 512          // topk collection capacity
#define NROW (B_ * N_)
#define TPB 256

// ---------------- device helpers ----------------

__device__ __forceinline__ void decode_box(const float* __restrict__ breg,
                                           const float* __restrict__ pbox,
                                           int row, int c, float* out) {
    float bx1 = pbox[row * 4 + 0];
    float by1 = pbox[row * 4 + 1];
    float bx2 = pbox[row * 4 + 2];
    float by2 = pbox[row * 4 + 3];
    float w  = bx2 - bx1 + 1.0f;
    float h  = by2 - by1 + 1.0f;
    float cx = bx1 + 0.5f * w;
    float cy = by1 + 0.5f * h;
    const float* r = breg + (size_t)row * (C_ * 4) + c * 4;
    float dx = r[0] / 10.0f;
    float dy = r[1] / 10.0f;
    float dw = fminf(r[2] / 5.0f, (float)XFORM_CLIP);
    float dh = fminf(r[3] / 5.0f, (float)XFORM_CLIP);
    float px = dx * w + cx;
    float py = dy * h + cy;
    float pw = expf(dw) * w;
    float ph = expf(dh) * h;
    float x1 = px - 0.5f * pw;
    float y1 = py - 0.5f * ph;
    float x2 = px + 0.5f * pw - 1.0f;
    float y2 = py + 0.5f * ph - 1.0f;
    out[0] = fminf(fmaxf(x1, 0.0f), IMG_W_M1);
    out[1] = fminf(fmaxf(y1, 0.0f), IMG_H_M1);
    out[2] = fminf(fmaxf(x2, 0.0f), IMG_W_M1);
    out[3] = fminf(fmaxf(y2, 0.0f), IMG_H_M1);
}

// ---------------- kernel 0: softmax -> TRANSPOSED prob [C][NROW] ----------------
// also zeroes count[] and done[] (replaces a memset node)

__global__ __launch_bounds__(256) void prob_k(const float* __restrict__ logits,
                                              float* __restrict__ probT,
                                              int* __restrict__ count,
                                              int* __restrict__ done) {
    if (blockIdx.x == 0 && threadIdx.x < B_) { count[threadIdx.x] = 0; done[threadIdx.x] = 0; }
    int row  = blockIdx.x * 4 + (threadIdx.x >> 6);
    int lane = threadIdx.x & 63;
    const float* rp = logits + (size_t)row * C_;
    float v0 = rp[lane];
    float v1 = (lane + 64 < C_) ? rp[lane + 64] : -INFINITY;
    float m = fmaxf(v0, v1);
    #pragma unroll
    for (int off = 32; off; off >>= 1) m = fmaxf(m, __shfl_xor(m, off));
    float e0 = expf(v0 - m);
    float e1 = (lane + 64 < C_) ? expf(v1 - m) : 0.0f;
    float s = e0 + e1;
    #pragma unroll
    for (int off = 32; off; off >>= 1) s += __shfl_xor(s, off);
    if (lane != 0) probT[(size_t)lane * NROW + row] = e0 / s;   // class 0 never read
    if (lane + 64 < C_) probT[(size_t)(lane + 64) * NROW + row] = e1 / s;
}

// ---------------- kernel 1: NMS + (last-arriver) per-image top-100 ----------------

__global__ __launch_bounds__(TPB) void nms_topk_k(const float* __restrict__ probT,
                                                  const float* __restrict__ breg,
                                                  const float* __restrict__ pbox,
                                                  float* __restrict__ cand_s,
                                                  int* __restrict__ cand_i,
                                                  int* __restrict__ count,
                                                  int* __restrict__ done,
                                                  float* __restrict__ out) {
    __shared__ float skey[N_];
    __shared__ int   sidx[N_];
    __shared__ float sx1[N_], sy1[N_], sx2[N_], sy2[N_], sar[N_];
    __shared__ unsigned rembits[64];
    __shared__ int   mcount;
    __shared__ int   is_last;
    // fast-path sorted arrays (M <= 64)
    __shared__ float fs[64];  __shared__ int ffi[64];
    __shared__ float fx1[64], fy1[64], fx2[64], fy2[64], far_[64];
    // topk shared
    __shared__ int   hist[HB];
    __shared__ int   ssum[HB];
    __shared__ float lsv[LCAP];
    __shared__ int   lfv[LCAP];
    __shared__ int   lcnt;
    __shared__ int   sel_t1;
    __shared__ float rs[TPB];
    __shared__ int   rf[TPB];
    __shared__ int   rp[TPB];

    int blk = blockIdx.x;
    int b   = blk / NFG;
    int c   = blk % NFG + 1;        // foreground class 1..80
    int tid = threadIdx.x;

    if (tid == 0) mcount = 0;
    __syncthreads();

    // ---- Phase A: coalesced column read + threshold compaction ----
    const float* col = probT + (size_t)c * NROW + b * N_;
    #pragma unroll
    for (int r = 0; r < N_ / TPB; ++r) {
        int n = tid + r * TPB;
        float s = col[n];
        if (s > SCORE_THRESH) {
            int p = atomicAdd(&mcount, 1);
            skey[p] = s;
            sidx[p] = n;
        }
    }
    __syncthreads();
    int M = mcount;   // uniform

    if (M > 0 && M <= 64) {
        // ---- stage 1: rank-by-count sort + decode own box -> sorted LDS slots ----
        if (tid < 64) {
            int lane = tid;
            if (lane < M) {
                float s = skey[lane];
                int idx = sidx[lane];
                int r = 0;
                for (int q = 0; q < M; ++q) {
                    float sq = skey[q]; int iq = sidx[q];
                    if (sq > s || (sq == s && iq < idx)) r++;
                }
                float bx[4];
                decode_box(breg, pbox, b * N_ + idx, c, bx);
                fs[r]  = s;
                ffi[r] = idx;
                fx1[r] = bx[0]; fy1[r] = bx[1]; fx2[r] = bx[2]; fy2[r] = bx[3];
                far_[r] = (bx[2] - bx[0] + 1.0f) * (bx[3] - bx[1] + 1.0f);
            }
        }
        __syncthreads();
        // ---- stage 2: adjacency build (pipelined LDS) + ballot greedy ----
        if (tid < 64) {
            int lane = tid;
            bool act = lane < M;
            float s = 0.0f, x1 = 0.f, y1 = 0.f, x2 = 0.f, y2 = 0.f, ar = 0.f;
            int idx = 0;
            if (act) {
                s = fs[lane]; idx = ffi[lane];
                x1 = fx1[lane]; y1 = fy1[lane]; x2 = fx2[lane]; y2 = fy2[lane];
                ar = far_[lane];
            }
            unsigned long long adj = 0ULL;
            for (int i = 0; i < M; ++i) {
                if (act && i < lane) {
                    float xx1 = fmaxf(x1, fx1[i]);
                    float yy1 = fmaxf(y1, fy1[i]);
                    float xx2 = fminf(x2, fx2[i]);
                    float yy2 = fminf(y2, fy2[i]);
                    float w = fmaxf(xx2 - xx1 + 1.0f, 0.0f);
                    float h = fmaxf(yy2 - yy1 + 1.0f, 0.0f);
                    float inter = w * h;
                    float iou = inter / (ar + far_[i] - inter);
                    if (iou > NMS_THRESH) adj |= 1ULL << i;
                }
            }
            // sequential greedy via ballot (register/SALU only)
            int rem = 0;
            for (int i = 0; i < M; ++i) {
                unsigned long long remmask = __ballot(rem != 0);
                if (!((remmask >> i) & 1ULL) && ((adj >> i) & 1ULL)) rem = 1;
            }
            // batched append of survivors
            unsigned long long keepmask = __ballot(act && !rem);
            int base = 0;
            if (lane == 0) base = atomicAdd(&count[b], __popcll(keepmask));
            base = __shfl(base, 0);
            if (act && !rem) {
                int pos = base + __popcll(keepmask & ((1ULL << lane) - 1ULL));
                cand_s[(size_t)b * CAND + pos] = s;
                cand_i[(size_t)b * CAND + pos] = idx * NFG + (c - 1);
            }
        }
    } else if (M > 64) {
        // ---- fallback: LDS bitonic + wave-0 bitmask NMS (rare) ----
        int P = 64;
        while (P < M) P <<= 1;
        for (int i = M + tid; i < P; i += TPB) { skey[i] = NEG_INF; sidx[i] = 0x7fffffff; }
        __syncthreads();
        for (int k = 2; k <= P; k <<= 1) {
            for (int j = k >> 1; j > 0; j >>= 1) {
                for (int i = tid; i < P; i += TPB) {
                    int l = i ^ j;
                    if (l > i) {
                        float ki = skey[i], kl = skey[l];
                        int   ii = sidx[i], il = sidx[l];
                        bool iFirst = (ki > kl) || (ki == kl && ii < il);
                        bool asc = ((i & k) == 0);
                        if (iFirst != asc) {
                            skey[i] = kl; skey[l] = ki;
                            sidx[i] = il; sidx[l] = ii;
                        }
                    }
                }
                __syncthreads();
            }
        }
        for (int i = tid; i < M; i += TPB) {
            float box[4];
            decode_box(breg, pbox, b * N_ + sidx[i], c, box);
            sx1[i] = box[0]; sy1[i] = box[1]; sx2[i] = box[2]; sy2[i] = box[3];
            sar[i] = (box[2] - box[0] + 1.0f) * (box[3] - box[1] + 1.0f);
        }
        __syncthreads();
        if (tid < 64) {
            int lane = tid;
            unsigned my = 0;
            for (int i = 0; i < M; ++i) {
                unsigned obits = __shfl(my, i & 63);
                bool kept = ((obits >> (i >> 6)) & 1u) == 0u;
                if (kept) {
                    float x1i = sx1[i], y1i = sy1[i], x2i = sx2[i], y2i = sy2[i], ai = sar[i];
                    for (int j = lane; j < M; j += 64) {
                        if (j > i && !((my >> (j >> 6)) & 1u)) {
                            float xx1 = fmaxf(x1i, sx1[j]);
                            float yy1 = fmaxf(y1i, sy1[j]);
                            float xx2 = fminf(x2i, sx2[j]);
                            float yy2 = fminf(y2i, sy2[j]);
                            float w = fmaxf(xx2 - xx1 + 1.0f, 0.0f);
                            float h = fmaxf(yy2 - yy1 + 1.0f, 0.0f);
                            float inter = w * h;
                            float iou = inter / (ai + sar[j] - inter);
                            if (iou > NMS_THRESH) my |= 1u << (j >> 6);
                        }
                    }
                }
            }
            rembits[lane] = my;
        }
        __syncthreads();
        for (int j = tid; j < M; j += TPB) {
            if (!((rembits[j & 63] >> (j >> 6)) & 1u)) {
                int pos = atomicAdd(&count[b], 1);
                cand_s[(size_t)b * CAND + pos] = skey[j];
                cand_i[(size_t)b * CAND + pos] = sidx[j] * NFG + (c - 1);
            }
        }
    }

    // ---- Phase C: last-arriver does the per-image top-100 ----
    __syncthreads();
    if (tid == 0) {
        __threadfence();                       // release: push cand writes
        int t = atomicAdd(&done[b], 1);        // device-scope RMW
        is_last = (t == NFG - 1) ? 1 : 0;
    }
    __syncthreads();
    if (!is_last) return;
    __threadfence();                           // acquire

    int M2 = count[b];
    float* cs = cand_s + (size_t)b * CAND;
    const int* ci = cand_i + (size_t)b * CAND;
    float* boxes_o  = out + (size_t)b * DETS * 4;
    float* scores_o = out + (size_t)B_ * DETS * 4 + (size_t)b * DETS;
    float* labels_o = out + (size_t)B_ * DETS * 4 + (size_t)B_ * DETS + (size_t)b * DETS;

    for (int i = tid; i < HB; i += TPB) hist[i] = 0;
    if (tid == 0) { lcnt = 0; sel_t1 = 0; }
    __syncthreads();

    // coarse histogram on float bit pattern (monotonic for positive floats)
    for (int i = tid; i < M2; i += TPB) {
        unsigned bits = __float_as_uint(cs[i]);
        int cb = (int)((bits - 0x3D000000u) >> 18);
        if (cb > HB - 1) cb = HB - 1;
        atomicAdd(&hist[cb], 1);
    }
    __syncthreads();

    // barrier-free suffix sums: ssum[bi] = sum_{j>=bi} hist[j]
    if (tid < HB) {
        int acc = 0;
        for (int j = tid; j < HB; ++j) acc += hist[j];
        ssum[tid] = acc;
    }
    __syncthreads();
    // unique-writer threshold bucket: largest bi with ssum[bi] >= DETS
    if (M2 > DETS && tid < HB) {
        if (ssum[tid] >= DETS && (tid == HB - 1 || ssum[tid + 1] < DETS)) sel_t1 = tid;
    }
    __syncthreads();
    int t1 = sel_t1;

    // collect all candidates at/above the boundary bucket
    for (int i = tid; i < M2; i += TPB) {
        float s = cs[i];
        unsigned bits = __float_as_uint(s);
        int cb = (int)((bits - 0x3D000000u) >> 18);
        if (cb > HB - 1) cb = HB - 1;
        if (cb >= t1) {
            int p = atomicAdd(&lcnt, 1);
            if (p < LCAP) { lsv[p] = s; lfv[p] = ci[i]; }
        }
    }
    __syncthreads();
    int L = lcnt;

    if (L <= LCAP) {
        // rank-by-counting: (score desc, flat idx asc) strict total order
        for (int e = tid; e < L; e += TPB) {
            float s = lsv[e]; int f = lfv[e];
            int r = 0;
            for (int q = 0; q < L; ++q) {
                float sq = lsv[q]; int fq = lfv[q];
                if (sq > s || (sq == s && fq < f)) r++;
            }
            if (r < DETS) {
                int n = f / NFG;
                int cc = f % NFG + 1;
                float box[4];
                decode_box(breg, pbox, b * N_ + n, cc, box);
                boxes_o[r * 4 + 0] = box[0];
                boxes_o[r * 4 + 1] = box[1];
                boxes_o[r * 4 + 2] = box[2];
                boxes_o[r * 4 + 3] = box[3];
                scores_o[r] = s;
                labels_o[r] = (float)cc;
            }
        }
        int start = (L < DETS) ? L : DETS;
        for (int r = tid; r < DETS; r += TPB) {
            if (r >= start) {
                boxes_o[r * 4 + 0] = 0.0f;
                boxes_o[r * 4 + 1] = 0.0f;
                boxes_o[r * 4 + 2] = 0.0f;
                boxes_o[r * 4 + 3] = 0.0f;
                scores_o[r] = 0.0f;
                labels_o[r] = -1.0f;
            }
        }
    } else {
        // pathological fallback: repeated argmax over global list
        for (int it = 0; it < DETS; ++it) {
            float bs = NEG_INF; int bf = 0x7fffffff; int bp = -1;
            for (int i = tid; i < M2; i += TPB) {
                float s = cs[i]; int f = ci[i];
                if (s > bs || (s == bs && f < bf)) { bs = s; bf = f; bp = i; }
            }
            rs[tid] = bs; rf[tid] = bf; rp[tid] = bp;
            __syncthreads();
            for (int off = TPB / 2; off; off >>= 1) {
                if (tid < off) {
                    if (rs[tid + off] > rs[tid] ||
                        (rs[tid + off] == rs[tid] && rf[tid + off] < rf[tid])) {
                        rs[tid] = rs[tid + off]; rf[tid] = rf[tid + off]; rp[tid] = rp[tid + off];
                    }
                }
                __syncthreads();
            }
            if (tid == 0) {
                float s = rs[0];
                bool valid = s > SCORE_THRESH;
                float box[4] = {0.f, 0.f, 0.f, 0.f};
                float lab = -1.0f, scv = 0.0f;
                if (valid) {
                    int fi = rf[0];
                    int n = fi / NFG;
                    int cc = fi % NFG + 1;
                    decode_box(breg, pbox, b * N_ + n, cc, box);
                    lab = (float)cc; scv = s;
                    cs[rp[0]] = NEG_INF;
                }
                boxes_o[it * 4 + 0] = box[0];
                boxes_o[it * 4 + 1] = box[1];
                boxes_o[it * 4 + 2] = box[2];
                boxes_o[it * 4 + 3] = box[3];
                scores_o[it] = scv;
                labels_o[it] = lab;
            }
            __syncthreads();
        }
    }
}

// ---------------- launch ----------------

extern "C" void kernel_launch(void* const* d_in, const int* in_sizes, int n_in,
                              void* d_out, int out_size, void* d_ws, size_t ws_size,
                              hipStream_t stream) {
    const float* logits = (const float*)d_in[0];   // [2048, 81]
    const float* breg   = (const float*)d_in[1];   // [2048, 324]
    const float* pbox   = (const float*)d_in[2];   // [2048, 4]
    float* out = (float*)d_out;                    // 800 boxes + 200 scores + 200 labels

    float* cand_s = (float*)d_ws;                         // B*CAND floats
    int*   cand_i = (int*)(cand_s + (size_t)B_ * CAND);   // B*CAND ints
    int*   count  = (int*)(cand_i + (size_t)B_ * CAND);   // [B]
    int*   done   = count + B_;                           // [B]
    float* probT  = (float*)(done + B_);                  // [C][NROW]

    prob_k<<<NROW / 4, 256, 0, stream>>>(logits, probT, count, done);
    nms_topk_k<<<B_ * NFG, TPB, 0, stream>>>(probT, breg, pbox, cand_s, cand_i,
                                             count, done, out);
}

// Round 10
// 37.944 us; speedup vs baseline: 1.0944x; 1.0944x over previous
//
#include <hip/hip_runtime.h>
#include <math.h>

#define B_ 2
#define N_ 1024
#define C_ 81
#define NFG 80            // foreground classes 1..80
#define DETS 100
#define CAND (N_ * NFG)   // per-image candidate capacity
#define SCORE_THRESH 0.05f
#define NMS_THRESH 0.5f
#define NEG_INF -1e30f
#define IMG_W_M1 1332.0f
#define IMG_H_M1 799.0f
#define XFORM_CLIP 4.135166556742356f   // log(1000/16)
#define HB 192            // coarse score-histogram buckets
#define LCAP 512          // topk collection capacity
#define NROW (B_ * N_)

// ---------------- device helpers ----------------

__device__ __forceinline__ void decode_box(const float* __restrict__ breg,
                                           const float* __restrict__ pbox,
                                           int row, int c, float* out) {
    float bx1 = pbox[row * 4 + 0];
    float by1 = pbox[row * 4 + 1];
    float bx2 = pbox[row * 4 + 2];
    float by2 = pbox[row * 4 + 3];
    float w  = bx2 - bx1 + 1.0f;
    float h  = by2 - by1 + 1.0f;
    float cx = bx1 + 0.5f * w;
    float cy = by1 + 0.5f * h;
    const float* r = breg + (size_t)row * (C_ * 4) + c * 4;
    float dx = r[0] / 10.0f;
    float dy = r[1] / 10.0f;
    float dw = fminf(r[2] / 5.0f, (float)XFORM_CLIP);
    float dh = fminf(r[3] / 5.0f, (float)XFORM_CLIP);
    float px = dx * w + cx;
    float py = dy * h + cy;
    float pw = expf(dw) * w;
    float ph = expf(dh) * h;
    float x1 = px - 0.5f * pw;
    float y1 = py - 0.5f * ph;
    float x2 = px + 0.5f * pw - 1.0f;
    float y2 = py + 0.5f * ph - 1.0f;
    out[0] = fminf(fmaxf(x1, 0.0f), IMG_W_M1);
    out[1] = fminf(fmaxf(y1, 0.0f), IMG_H_M1);
    out[2] = fminf(fmaxf(x2, 0.0f), IMG_W_M1);
    out[3] = fminf(fmaxf(y2, 0.0f), IMG_H_M1);
}

// ---------------- kernel 0: softmax -> TRANSPOSED prob [C][NROW] ----------------
// also zeroes the per-image candidate counters (replaces a memset node)

__global__ __launch_bounds__(256) void prob_k(const float* __restrict__ logits,
                                              float* __restrict__ probT,
                                              int* __restrict__ count) {
    if (blockIdx.x == 0 && threadIdx.x < B_) count[threadIdx.x] = 0;
    int row  = blockIdx.x * 4 + (threadIdx.x >> 6);
    int lane = threadIdx.x & 63;
    const float* rp = logits + (size_t)row * C_;
    float v0 = rp[lane];
    float v1 = (lane + 64 < C_) ? rp[lane + 64] : -INFINITY;
    float m = fmaxf(v0, v1);
    #pragma unroll
    for (int off = 32; off; off >>= 1) m = fmaxf(m, __shfl_xor(m, off));
    float e0 = expf(v0 - m);
    float e1 = (lane + 64 < C_) ? expf(v1 - m) : 0.0f;
    float s = e0 + e1;
    #pragma unroll
    for (int off = 32; off; off >>= 1) s += __shfl_xor(s, off);
    probT[(size_t)lane * NROW + row] = e0 / s;
    if (lane + 64 < C_) probT[(size_t)(lane + 64) * NROW + row] = e1 / s;
}

// ---------------- kernel 1: per (image, class) greedy NMS ----------------

__global__ __launch_bounds__(256) void nms_k(const float* __restrict__ probT,
                                             const float* __restrict__ breg,
                                             const float* __restrict__ pbox,
                                             float* __restrict__ cand_s,
                                             int* __restrict__ cand_i,
                                             int* __restrict__ count) {
    __shared__ float skey[N_];
    __shared__ int   sidx[N_];
    __shared__ float sx1[N_], sy1[N_], sx2[N_], sy2[N_], sar[N_];
    __shared__ unsigned rembits[64];
    __shared__ int   mcount;

    int blk = blockIdx.x;
    int b   = blk / NFG;
    int c   = blk % NFG + 1;        // foreground class 1..80
    int tid = threadIdx.x;

    if (tid == 0) mcount = 0;
    __syncthreads();

    // ---- Phase A: coalesced column read + threshold compaction ----
    const float* col = probT + (size_t)c * NROW + b * N_;
    #pragma unroll
    for (int r = 0; r < N_ / 256; ++r) {
        int n = tid + r * 256;
        float s = col[n];
        if (s > SCORE_THRESH) {
            int p = atomicAdd(&mcount, 1);
            skey[p] = s;
            sidx[p] = n;
        }
    }
    __syncthreads();
    int M = mcount;   // uniform

    if (M > 0 && M <= 64) {
        // ---- fast path: sort + NMS entirely in wave-0 registers ----
        if (tid < 64) {
            int lane = tid;
            unsigned long long key;
            if (lane < M)
                key = ((unsigned long long)(~__float_as_uint(skey[lane])) << 32) |
                      (unsigned)sidx[lane];
            else
                key = ~0ULL;
            // 64-lane bitonic sort, ascending key == (score desc, idx asc)
            #pragma unroll
            for (int k = 2; k <= 64; k <<= 1) {
                #pragma unroll
                for (int j = k >> 1; j > 0; j >>= 1) {
                    unsigned long long other = __shfl_xor(key, j);
                    bool lower    = (lane & j) == 0;
                    bool dir_asc  = (lane & k) == 0;
                    bool keep_min = (dir_asc == lower);
                    bool mine_min = key < other;
                    key = (keep_min == mine_min) ? key : other;
                }
            }
            float sc = __uint_as_float(~(unsigned)(key >> 32));
            int   n  = (int)(unsigned)(key & 0xFFFFFFFFu);
            float bx[4]; float area = 0.0f; int rem = 0;
            if (lane < M) {
                decode_box(breg, pbox, b * N_ + n, c, bx);
                area = (bx[2] - bx[0] + 1.0f) * (bx[3] - bx[1] + 1.0f);
            }
            // greedy NMS via shuffle broadcast (no barriers)
            for (int i = 0; i < M; ++i) {
                int   rem_i = __shfl(rem, i);
                float x1i = __shfl(bx[0], i);
                float y1i = __shfl(bx[1], i);
                float x2i = __shfl(bx[2], i);
                float y2i = __shfl(bx[3], i);
                float ai  = __shfl(area, i);
                if (!rem_i && lane > i && lane < M && !rem) {
                    float xx1 = fmaxf(x1i, bx[0]);
                    float yy1 = fmaxf(y1i, bx[1]);
                    float xx2 = fminf(x2i, bx[2]);
                    float yy2 = fminf(y2i, bx[3]);
                    float w = fmaxf(xx2 - xx1 + 1.0f, 0.0f);
                    float h = fmaxf(yy2 - yy1 + 1.0f, 0.0f);
                    float inter = w * h;
                    float iou = inter / (area + ai - inter);
                    if (iou > NMS_THRESH) rem = 1;
                }
            }
            // batched append of survivors
            unsigned long long keepmask = __ballot(lane < M && !rem);
            int base = 0;
            if (lane == 0) base = atomicAdd(&count[b], __popcll(keepmask));
            base = __shfl(base, 0);
            if (lane < M && !rem) {
                int pos = base + __popcll(keepmask & ((1ULL << lane) - 1ULL));
                cand_s[(size_t)b * CAND + pos] = sc;
                cand_i[(size_t)b * CAND + pos] = n * NFG + (c - 1);
            }
        }
    } else if (M > 64) {
        // ---- fallback: LDS bitonic + wave-0 bitmask NMS (rare) ----
        int P = 64;
        while (P < M) P <<= 1;
        for (int i = M + tid; i < P; i += 256) { skey[i] = NEG_INF; sidx[i] = 0x7fffffff; }
        __syncthreads();
        for (int k = 2; k <= P; k <<= 1) {
            for (int j = k >> 1; j > 0; j >>= 1) {
                for (int i = tid; i < P; i += 256) {
                    int l = i ^ j;
                    if (l > i) {
                        float ki = skey[i], kl = skey[l];
                        int   ii = sidx[i], il = sidx[l];
                        bool iFirst = (ki > kl) || (ki == kl && ii < il);
                        bool asc = ((i & k) == 0);
                        if (iFirst != asc) {
                            skey[i] = kl; skey[l] = ki;
                            sidx[i] = il; sidx[l] = ii;
                        }
                    }
                }
                __syncthreads();
            }
        }
        for (int i = tid; i < M; i += 256) {
            float box[4];
            decode_box(breg, pbox, b * N_ + sidx[i], c, box);
            sx1[i] = box[0]; sy1[i] = box[1]; sx2[i] = box[2]; sy2[i] = box[3];
            sar[i] = (box[2] - box[0] + 1.0f) * (box[3] - box[1] + 1.0f);
        }
        __syncthreads();
        if (tid < 64) {
            int lane = tid;
            unsigned my = 0;
            for (int i = 0; i < M; ++i) {
                unsigned obits = __shfl(my, i & 63);
                bool kept = ((obits >> (i >> 6)) & 1u) == 0u;
                if (kept) {
                    float x1i = sx1[i], y1i = sy1[i], x2i = sx2[i], y2i = sy2[i], ai = sar[i];
                    for (int j = lane; j < M; j += 64) {
                        if (j > i && !((my >> (j >> 6)) & 1u)) {
                            float xx1 = fmaxf(x1i, sx1[j]);
                            float yy1 = fmaxf(y1i, sy1[j]);
                            float xx2 = fminf(x2i, sx2[j]);
                            float yy2 = fminf(y2i, sy2[j]);
                            float w = fmaxf(xx2 - xx1 + 1.0f, 0.0f);
                            float h = fmaxf(yy2 - yy1 + 1.0f, 0.0f);
                            float inter = w * h;
                            float iou = inter / (ai + sar[j] - inter);
                            if (iou > NMS_THRESH) my |= 1u << (j >> 6);
                        }
                    }
                }
            }
            rembits[lane] = my;
        }
        __syncthreads();
        for (int j = tid; j < M; j += 256) {
            if (!((rembits[j & 63] >> (j >> 6)) & 1u)) {
                int pos = atomicAdd(&count[b], 1);
                cand_s[(size_t)b * CAND + pos] = skey[j];
                cand_i[(size_t)b * CAND + pos] = sidx[j] * NFG + (c - 1);
            }
        }
    }
}

// ---------------- kernel 2: per-image top-100 via histogram select ----------------

#define TTPB 512

__global__ __launch_bounds__(TTPB) void topk_k(float* __restrict__ cand_s,
                                               const int* __restrict__ cand_i,
                                               const int* __restrict__ count,
                                               const float* __restrict__ breg,
                                               const float* __restrict__ pbox,
                                               float* __restrict__ out) {
    __shared__ int   hist[HB];
    __shared__ int   ssum[HB];
    __shared__ float lsv[LCAP];
    __shared__ int   lfv[LCAP];
    __shared__ int   lcnt;
    __shared__ int   sel_t1;
    __shared__ float rs[TTPB];
    __shared__ int   rf[TTPB];
    __shared__ int   rp[TTPB];

    int b   = blockIdx.x;
    int tid = threadIdx.x;
    int M2  = count[b];
    float* cs = cand_s + (size_t)b * CAND;
    const int* ci = cand_i + (size_t)b * CAND;
    float* boxes_o  = out + (size_t)b * DETS * 4;
    float* scores_o = out + (size_t)B_ * DETS * 4 + (size_t)b * DETS;
    float* labels_o = out + (size_t)B_ * DETS * 4 + (size_t)B_ * DETS + (size_t)b * DETS;

    for (int i = tid; i < HB; i += TTPB) hist[i] = 0;
    if (tid == 0) { lcnt = 0; sel_t1 = 0; }
    __syncthreads();

    // coarse histogram on float bit pattern (monotonic for positive floats)
    for (int i = tid; i < M2; i += TTPB) {
        unsigned bits = __float_as_uint(cs[i]);
        int cb = (int)((bits - 0x3D000000u) >> 18);
        if (cb > HB - 1) cb = HB - 1;
        atomicAdd(&hist[cb], 1);
    }
    __syncthreads();

    // barrier-free suffix sums: ssum[bi] = sum_{j>=bi} hist[j]
    if (tid < HB) {
        int acc = 0;
        for (int j = tid; j < HB; ++j) acc += hist[j];
        ssum[tid] = acc;
    }
    __syncthreads();
    // unique-writer threshold bucket: largest bi with ssum[bi] >= DETS
    if (M2 > DETS && tid < HB) {
        if (ssum[tid] >= DETS && (tid == HB - 1 || ssum[tid + 1] < DETS)) sel_t1 = tid;
    }
    __syncthreads();
    int t1 = sel_t1;

    // collect all candidates at/above the boundary bucket
    for (int i = tid; i < M2; i += TTPB) {
        float s = cs[i];
        unsigned bits = __float_as_uint(s);
        int cb = (int)((bits - 0x3D000000u) >> 18);
        if (cb > HB - 1) cb = HB - 1;
        if (cb >= t1) {
            int p = atomicAdd(&lcnt, 1);
            if (p < LCAP) { lsv[p] = s; lfv[p] = ci[i]; }
        }
    }
    __syncthreads();
    int L = lcnt;

    if (L <= LCAP) {
        // rank-by-counting: (score desc, flat idx asc) strict total order
        for (int e = tid; e < L; e += TTPB) {
            float s = lsv[e]; int f = lfv[e];
            int r = 0;
            for (int q = 0; q < L; ++q) {
                float sq = lsv[q]; int fq = lfv[q];
                if (sq > s || (sq == s && fq < f)) r++;
            }
            if (r < DETS) {
                int n = f / NFG;
                int cc = f % NFG + 1;
                float box[4];
                decode_box(breg, pbox, b * N_ + n, cc, box);
                boxes_o[r * 4 + 0] = box[0];
                boxes_o[r * 4 + 1] = box[1];
                boxes_o[r * 4 + 2] = box[2];
                boxes_o[r * 4 + 3] = box[3];
                scores_o[r] = s;
                labels_o[r] = (float)cc;
            }
        }
        int start = (L < DETS) ? L : DETS;
        for (int r = tid; r < DETS; r += TTPB) {
            if (r >= start) {
                boxes_o[r * 4 + 0] = 0.0f;
                boxes_o[r * 4 + 1] = 0.0f;
                boxes_o[r * 4 + 2] = 0.0f;
                boxes_o[r * 4 + 3] = 0.0f;
                scores_o[r] = 0.0f;
                labels_o[r] = -1.0f;
            }
        }
    } else {
        // pathological fallback: repeated argmax over global list
        for (int it = 0; it < DETS; ++it) {
            float bs = NEG_INF; int bf = 0x7fffffff; int bp = -1;
            for (int i = tid; i < M2; i += TTPB) {
                float s = cs[i]; int f = ci[i];
                if (s > bs || (s == bs && f < bf)) { bs = s; bf = f; bp = i; }
            }
            rs[tid] = bs; rf[tid] = bf; rp[tid] = bp;
            __syncthreads();
            for (int off = TTPB / 2; off; off >>= 1) {
                if (tid < off) {
                    if (rs[tid + off] > rs[tid] ||
                        (rs[tid + off] == rs[tid] && rf[tid + off] < rf[tid])) {
                        rs[tid] = rs[tid + off]; rf[tid] = rf[tid + off]; rp[tid] = rp[tid + off];
                    }
                }
                __syncthreads();
            }
            if (tid == 0) {
                float s = rs[0];
                bool valid = s > SCORE_THRESH;
                float box[4] = {0.f, 0.f, 0.f, 0.f};
                float lab = -1.0f, scv = 0.0f;
                if (valid) {
                    int fi = rf[0];
                    int n = fi / NFG;
                    int cc = fi % NFG + 1;
                    decode_box(breg, pbox, b * N_ + n, cc, box);
                    lab = (float)cc; scv = s;
                    cs[rp[0]] = NEG_INF;
                }
                boxes_o[it * 4 + 0] = box[0];
                boxes_o[it * 4 + 1] = box[1];
                boxes_o[it * 4 + 2] = box[2];
                boxes_o[it * 4 + 3] = box[3];
                scores_o[it] = scv;
                labels_o[it] = lab;
            }
            __syncthreads();
        }
    }
}

// ---------------- launch ----------------

extern "C" void kernel_launch(void* const* d_in, const int* in_sizes, int n_in,
                              void* d_out, int out_size, void* d_ws, size_t ws_size,
                              hipStream_t stream) {
    const float* logits = (const float*)d_in[0];   // [2048, 81]
    const float* breg   = (const float*)d_in[1];   // [2048, 324]
    const float* pbox   = (const float*)d_in[2];   // [2048, 4]
    float* out = (float*)d_out;                    // 800 boxes + 200 scores + 200 labels

    float* cand_s = (float*)d_ws;                         // B*CAND floats
    int*   cand_i = (int*)(cand_s + (size_t)B_ * CAND);   // B*CAND ints
    int*   count  = (int*)(cand_i + (size_t)B_ * CAND);   // [B]
    float* probT  = (float*)(count + 2);                  // [C][NROW]

    prob_k<<<NROW / 4, 256, 0, stream>>>(logits, probT, count);
    nms_k<<<B_ * NFG, 256, 0, stream>>>(probT, breg, pbox, cand_s, cand_i, count);
    topk_k<<<B_, TTPB, 0, stream>>>(cand_s, cand_i, count, breg, pbox, out);
}